// Round 14
// baseline (1009.144 us; speedup 1.0000x reference)
//
#include <hip/hip_runtime.h>
#include <hip/hip_bf16.h>
#include <cstdint>
#include <cstddef>

#define A_REAL 50000
#define A_PAD  50176      // 196 * 256
#define MT256  196
#define PADROWS 176
#define NBOND  6
#define HD     512
#define FATOM  133
#define FBOND  14
#define KWI    160        // f_atoms block width (133 padded)
#define KU     704        // unified row: nei(512) | bond(32) | f_atoms(160)
#define NMOL   2000
#define MOLPAD 2048
#define APM    25
#define NHID   256

typedef __bf16 bf16x8 __attribute__((ext_vector_type(8)));
typedef float  f32x4  __attribute__((ext_vector_type(4)));
typedef short  short8 __attribute__((ext_vector_type(8)));
typedef short  short4v __attribute__((ext_vector_type(4)));

__device__ __forceinline__ float b2f(unsigned short u) {
  return __uint_as_float(((unsigned int)u) << 16);
}
__device__ __forceinline__ unsigned short f2b(float f) {
  unsigned int x = __float_as_uint(f);
  unsigned int r = (x + 0x7fffu + ((x >> 16) & 1u)) >> 16;
  return (unsigned short)r;
}
__device__ __forceinline__ unsigned short f2h(float f) {
  _Float16 h = (_Float16)f;                 // v_cvt_f16_f32, RNE
  return *(unsigned short*)&h;
}
__device__ __forceinline__ float h2f(unsigned short u) {
  _Float16 h = *(_Float16*)&u;
  return (float)h;
}

// ---------------- zero pad rows of wU (both sides) + wEnc pad ----------------
__global__ void zero_pads(unsigned short* __restrict__ wU, unsigned long long sU,
                          unsigned short* __restrict__ wEnc)
{
  const int t = blockIdx.x * 256 + threadIdx.x;
  if (t < PADROWS * KU) {
    wU[(size_t)A_REAL * KU + t] = 0;
    wU[sU + (size_t)A_REAL * KU + t] = 0;
  }
  if (t < 48 * 1024) wEnc[(size_t)NMOL * 1024 + t] = 0;
}

// ---------------- f32 weights -> padded bf16 ---------------------------------
// mode 0: plain pad. mode 1: Wo -> KU layout. mode 2: Wh+Wi combined -> KU.
__global__ void convw(unsigned short* __restrict__ dst, const float* __restrict__ src,
                      const float* __restrict__ srcB,
                      int Ksrc, int ldd, int rows, int mode)
{
  const int idx = blockIdx.x * 256 + threadIdx.x;
  if (idx >= rows * ldd) return;
  const int n = idx / ldd, k = idx % ldd;
  float v = 0.f;
  if (mode == 0) {
    if (k < Ksrc) v = src[(size_t)n * Ksrc + k];
  } else if (mode == 1) {
    if (k < 512)                  v = src[(size_t)n * 645 + 133 + k];
    else if (k >= 544 && k < 677) v = src[(size_t)n * 645 + (k - 544)];
  } else {
    if (k < 526)                  v = src[(size_t)n * 526 + k];
    else if (k >= 544 && k < 677) v = srcB[(size_t)n * 133 + (k - 544)];
  }
  dst[(size_t)n * ldd + k] = f2b(v);
}

// ---------------- combined bias bh + bi (f32) --------------------------------
__global__ void bias_comb(float* __restrict__ dst, const float* __restrict__ bh,
                          const float* __restrict__ bi)
{
  const int t = blockIdx.x * 256 + threadIdx.x;
  if (t < HD) dst[t] = bh[t] + bi[t];
}

// ---------------- f_atoms -> wU cols 544..703 (bf16, padded) -----------------
__global__ void atoms_prep(unsigned short* __restrict__ wU, const float* __restrict__ f_atoms)
{
  const int idx = blockIdx.x * 256 + threadIdx.x;
  if (idx >= A_PAD * KWI) return;
  const int r = idx / KWI, c = idx % KWI;
  float v = 0.f;
  if (r < A_REAL && c < FATOM) v = f_atoms[(size_t)r * FATOM + c];
  wU[(size_t)r * KU + 544 + c] = f2b(v);
}

// ---------------- bond gather-sum -> wU cols 512..543 (once per side) --------
__global__ void bond_gather(unsigned short* __restrict__ wU, const float* __restrict__ f_bonds,
                            const int* __restrict__ a2b)
{
  const int a = blockIdx.x * 256 + threadIdx.x;
  if (a >= A_REAL) return;
  float acc[FBOND];
  #pragma unroll
  for (int c = 0; c < FBOND; ++c) acc[c] = 0.f;
  #pragma unroll
  for (int j = 0; j < NBOND; ++j) {
    const int b = a2b[a * NBOND + j];
    const float* row = f_bonds + (size_t)b * FBOND;
    #pragma unroll
    for (int c = 0; c < FBOND; ++c) acc[c] += row[c];
  }
  unsigned short* d = wU + (size_t)a * KU + 512;
  #pragma unroll
  for (int c = 0; c < FBOND; ++c) d[c] = f2b(acc[c]);
  #pragma unroll
  for (int c = FBOND; c < 32; ++c) d[c] = 0;
}

// ============ SLOT KERNEL: role-split co-dispatch, 1:1 interleave ============
// r13 post-mortem: every-9th interleave put only ~85/784 GEMM blocks in the
// initial resident set -> slot degenerated to gather-time + GEMM-tail
// (~100us vs 58us solo GEMM). r14: EQUAL-GRANULARITY 1:1 interleave --
// TOTAL = 2*GB blocks, bid&1 picks role; gather repacked into GB blocks of
// 64 atoms (8 waves x 8 atoms, same coalesced 1KB-row pattern). Every CU
// holds ~1.5 GEMM + ~1.5 gather blocks for the WHOLE slot -> true wave-level
// overlap (m114), no single-role tail. Numerics identical -> absmax 0.015625.
// GEMM: C[M x N] = A[M x K] * W[N x K]^T, bf16 in, fp32 accum, fp16 out.
// MODE 0: out = fp16(acc + bias)   MODE 2: out = fp16(relu(acc + bias))
struct SlotP {
  // gemm role (single side, pre-resolved pointers)
  const unsigned short* A; int lda;
  const unsigned short* W; int ldb;
  const float* bias;
  unsigned short* out; int outLd;
  int K; int gB; int R;
  // gather role (other side), active when R > 1
  unsigned short* gDst;               // side's wU (nei cols 0..511)
  const unsigned short* gState;       // side's fp16 state
  const int* a2a;
};

template<int MODE, int NTN>
__launch_bounds__(512, 4)
__global__ void slot_kernel(SlotP p)
{
  __shared__ alignas(16) unsigned short lA[2][256 * 32];
  __shared__ alignas(16) unsigned short lB[2][128 * 32];
  const int tid = threadIdx.x;
  const int bid = blockIdx.x;

  int gi = bid;
  bool isg = true;
  int hi = 0;
  if (p.R > 1) {
    if (bid & 1) { isg = false; hi = bid >> 1; }
    else         { gi = bid >> 1; }
  }

  if (!isg) {
    // ---- gather role: 64 atoms/block, 8 waves x 8 atoms (r11 pattern) ----
    const int wv   = tid >> 6;
    const int lane = tid & 63;
    #pragma unroll
    for (int k = 0; k < 8; ++k) {
      const int a = hi * 64 + wv * 8 + k;
      if (a < A_REAL) {
        const int* idx = p.a2a + a * NBOND;
        float acc[8] = {0.f,0.f,0.f,0.f,0.f,0.f,0.f,0.f};
        #pragma unroll
        for (int j = 0; j < NBOND; ++j) {
          const int r0 = idx[j];
          short8 v = *reinterpret_cast<const short8*>(p.gState + (size_t)r0 * HD + lane * 8);
          #pragma unroll
          for (int e = 0; e < 8; ++e) acc[e] += fmaxf(h2f((unsigned short)v[e]), 0.f);
        }
        short8 o;
        #pragma unroll
        for (int e = 0; e < 8; ++e) o[e] = (short)f2b(acc[e]);
        *reinterpret_cast<short8*>(p.gDst + (size_t)a * KU + lane * 8) = o;
      }
    }
    return;
  }

  // ---- gemm role: r11 body (ring-2, T2 swizzle, setprio) ----
  const int lane = tid & 63;
  const int wav  = tid >> 6;
  const int wm = wav >> 1, wn = wav & 1;

  // bijective chunked XCD swizzle over gemm sub-grid (gB % 8 == 0)
  const int nwg = p.gB;
  const int q2 = nwg >> 3, r2 = nwg & 7;
  const int xcd = gi & 7, jj = gi >> 3;
  const int gid = (xcd < r2 ? xcd * (q2 + 1) : r2 * (q2 + 1) + (xcd - r2) * q2) + jj;
  const int bxt = gid / NTN;
  const int byt = gid - bxt * NTN;
  const size_t tileM = (size_t)bxt * 256;
  const int n0 = byt * 128;

  const int srow = tid >> 2;
  const int sgcol = (((tid & 3) ^ ((tid >> 3) & 3)) * 8);  // T2 pre-swizzled chunk
  const int fr = lane & 15;
  const int xr = ((lane & 15) >> 1) & 3;
  const int fks = (((lane >> 4) ^ xr) * 8);

  f32x4 acc[4][4];
  #pragma unroll
  for (int m = 0; m < 4; ++m)
    #pragma unroll
    for (int n = 0; n < 4; ++n)
      acc[m][n] = (f32x4){0.f, 0.f, 0.f, 0.f};

  const unsigned short* Abase = p.A + tileM * (size_t)p.lda;
  const unsigned short* Wbase = p.W + (size_t)n0 * (size_t)p.ldb;
  const int lda = p.lda, ldb = p.ldb;
  const int nt = p.K >> 5;

  auto stage = [&](int t, int buf) {
    const int k0 = t * 32;
    #pragma unroll
    for (int i = 0; i < 2; ++i) {
      const int rr = i * 128 + srow;
      const unsigned short* ga = Abase + (size_t)rr * lda + (k0 + sgcol);
      __builtin_amdgcn_global_load_lds(
          (const __attribute__((address_space(1))) unsigned int*)ga,
          (__attribute__((address_space(3))) unsigned int*)&lA[buf][rr * 32 + (tid & 3) * 8], 16, 0, 0);
    }
    const unsigned short* gb = Wbase + (size_t)srow * ldb + (k0 + sgcol);
    __builtin_amdgcn_global_load_lds(
        (const __attribute__((address_space(1))) unsigned int*)gb,
        (__attribute__((address_space(3))) unsigned int*)&lB[buf][srow * 32 + (tid & 3) * 8], 16, 0, 0);
  };

  stage(0, 0);

  int buf = 0;
  for (int t = 0; t < nt; ++t) {
    asm volatile("s_waitcnt vmcnt(0)" ::: "memory");
    __builtin_amdgcn_s_barrier();
    asm volatile("" ::: "memory");

    bf16x8 af[4], bfm[4];
    #pragma unroll
    for (int m = 0; m < 4; ++m)
      af[m] = *reinterpret_cast<const bf16x8*>(&lA[buf][(wm * 64 + m * 16 + fr) * 32 + fks]);
    #pragma unroll
    for (int n = 0; n < 4; ++n)
      bfm[n] = *reinterpret_cast<const bf16x8*>(&lB[buf][(wn * 64 + n * 16 + fr) * 32 + fks]);

    if (t + 1 < nt) stage(t + 1, buf ^ 1);

    __builtin_amdgcn_s_setprio(1);
    // operand-swapped: lane = M-row, 4 acc regs = 4 consecutive N cols
    #pragma unroll
    for (int m = 0; m < 4; ++m)
      #pragma unroll
      for (int n = 0; n < 4; ++n)
        acc[m][n] = __builtin_amdgcn_mfma_f32_16x16x32_bf16(bfm[n], af[m], acc[m][n], 0, 0, 0);
    __builtin_amdgcn_s_setprio(0);

    buf ^= 1;
  }

  const int erow = lane & 15;
  const int ecol = (lane >> 4) * 4;
  #pragma unroll
  for (int m = 0; m < 4; ++m) {
    const size_t rowg = tileM + wm * 64 + m * 16 + erow;
    #pragma unroll
    for (int n = 0; n < 4; ++n) {
      const int colg = n0 + wn * 64 + n * 16 + ecol;
      const f32x4 bv = *reinterpret_cast<const f32x4*>(&p.bias[colg]);
      const size_t off = rowg * (size_t)p.outLd + colg;
      float v[4];
      #pragma unroll
      for (int e = 0; e < 4; ++e) v[e] = acc[m][n][e] + bv[e];
      short4v o;
      if (MODE == 0) {
        #pragma unroll
        for (int e = 0; e < 4; ++e) o[e] = (short)f2h(v[e]);
      } else {
        #pragma unroll
        for (int e = 0; e < 4; ++e) o[e] = (short)f2h(fmaxf(v[e], 0.f));
      }
      *reinterpret_cast<short4v*>(&p.out[off]) = o;
    }
  }
}

// ---------------- per-molecule mean over 25 atoms -> enc (bf16), dual-side ---
__launch_bounds__(256)
__global__ void readout(const unsigned short* __restrict__ h, unsigned long long sH,
                        unsigned short* __restrict__ enc, int bps)
{
  const int blk = blockIdx.x;
  const int s   = blk / bps;
  const int mol = blk - s * bps;
  const int t = threadIdx.x;
  const unsigned short* base = h + s * sH + (size_t)mol * APM * HD + t * 2;
  float s0 = 0.f, s1 = 0.f;
  #pragma unroll
  for (int r = 0; r < APM; ++r) {
    unsigned int v = *reinterpret_cast<const unsigned int*>(base + (size_t)r * HD);
    s0 += h2f((unsigned short)(v & 0xffffu));
    s1 += h2f((unsigned short)(v >> 16));
  }
  s0 *= (1.f / 25.f);
  s1 *= (1.f / 25.f);
  unsigned int o = (unsigned int)f2b(s0) | ((unsigned int)f2b(s1) << 16);
  *reinterpret_cast<unsigned int*>(enc + (size_t)mol * 1024 + s * HD + t * 2) = o;
}

// ---------------- final dot with ffn2 (ff1 is fp16) --------------------------
__launch_bounds__(256)
__global__ void ffn2_red(const unsigned short* __restrict__ ff1, const float* __restrict__ w2,
                         const float* __restrict__ b2, float* __restrict__ out)
{
  __shared__ float red[256];
  const int mol = blockIdx.x, t = threadIdx.x;
  red[t] = h2f(ff1[(size_t)mol * NHID + t]) * w2[t];
  __syncthreads();
  #pragma unroll
  for (int s = 128; s > 0; s >>= 1) {
    if (t < s) red[t] += red[t + s];
    __syncthreads();
  }
  if (t == 0) out[mol] = red[0] + b2[0];
}

// -----------------------------------------------------------------------------
extern "C" void kernel_launch(void* const* d_in, const int* in_sizes, int n_in,
                              void* d_out, int out_size, void* d_ws, size_t ws_size,
                              hipStream_t stream)
{
  (void)in_sizes; (void)n_in; (void)out_size; (void)ws_size;

  unsigned char* p = (unsigned char*)d_ws;
  auto take = [&](size_t bytes) -> unsigned short* {
    unsigned short* r = (unsigned short*)p;
    p += (bytes + 1023) & ~(size_t)1023;
    return r;
  };
  const unsigned long long sX = (unsigned long long)A_PAD * HD;   // elems
  const unsigned long long sU = (unsigned long long)A_PAD * KU;
  unsigned short* wS   = take((size_t)2 * sX * 2);   // fp16 state s / h
  unsigned short* wU   = take((size_t)2 * sU * 2);   // bf16 [nei|bond|f_atoms]
  unsigned short* wEnc = take((size_t)MOLPAD * 1024 * 2);   // bf16
  unsigned short* wFF1 = take((size_t)MOLPAD * NHID * 2);   // fp16
  unsigned short* wWiB = take((size_t)2 * 512 * KWI * 2);
  unsigned short* wWhC = take((size_t)2 * 512 * KU * 2);    // [Wh|0|Wi]
  unsigned short* wWoB = take((size_t)2 * 512 * KU * 2);
  unsigned short* wF1B = take((size_t)NHID * 1024 * 2);
  float*          wBC  = (float*)take((size_t)2 * HD * 4);  // bh+bi

  unsigned short* wS0 = wS;            unsigned short* wS1 = wS + sX;
  unsigned short* wU0 = wU;            unsigned short* wU1 = wU + sU;

  const float* biasWi[2]; const float* biasWo[2];
  const int* a2aP[2];
  for (int s = 0; s < 2; ++s) {
    biasWi[s] = (const float*)d_in[s * 10 + 5];
    biasWo[s] = (const float*)d_in[s * 10 + 9];
    a2aP[s]   = (const int*)  d_in[s * 10 + 2];
  }

  zero_pads<<<484, 256, 0, stream>>>(wU, sU, wEnc);

  for (int side = 0; side < 2; ++side) {
    const float* f_atoms = (const float*)d_in[side * 10 + 0];
    const float* f_bonds = (const float*)d_in[side * 10 + 1];
    const int*   a2b     = (const int*)  d_in[side * 10 + 3];
    const float* Wi_w    = (const float*)d_in[side * 10 + 4];
    const float* Wi_b    = (const float*)d_in[side * 10 + 5];
    const float* Wh_w    = (const float*)d_in[side * 10 + 6];
    const float* Wh_b    = (const float*)d_in[side * 10 + 7];
    const float* Wo_w    = (const float*)d_in[side * 10 + 8];
    convw<<<(512 * KWI) / 256, 256, 0, stream>>>(wWiB + side * 512 * KWI, Wi_w, nullptr,
                                                 FATOM, KWI, 512, 0);
    convw<<<(512 * KU) / 256, 256, 0, stream>>>(wWhC + side * 512 * KU, Wh_w, Wi_w,
                                                526, KU, 512, 2);
    convw<<<(512 * KU) / 256, 256, 0, stream>>>(wWoB + side * 512 * KU, Wo_w, nullptr,
                                                645, KU, 512, 1);
    bias_comb<<<2, 256, 0, stream>>>(wBC + side * HD, Wh_b, Wi_b);
    atoms_prep<<<(A_PAD * KWI) / 256, 256, 0, stream>>>(wU + side * sU, f_atoms);
    bond_gather<<<(A_REAL + 255) / 256, 256, 0, stream>>>(wU + side * sU, f_bonds, a2b);
  }

  const int GB = MT256 * 4;        // 784 gemm blocks (per side)
  const int TOTAL = GB * 2;        // 1568: 1:1 GEMM/gather interleave

  unsigned short* uS[2] = { wU0, wU1 };
  unsigned short* sS[2] = { wS0, wS1 };
  const unsigned short* whc[2] = { wWhC, wWhC + 512 * KU };
  const unsigned short* wob[2] = { wWoB, wWoB + 512 * KU };
  const unsigned short* wib[2] = { wWiB, wWiB + 512 * KWI };
  const float* bc[2] = { wBC, wBC + HD };

  SlotP s;
  // S1: Wi_sol (gemm only)
  s = { uS[0] + 544, KU, wib[0], KWI, biasWi[0], sS[0], HD, KWI, GB, 1,
        nullptr, nullptr, nullptr };
  slot_kernel<0, 4><<<GB, 512, 0, stream>>>(s);
  // S2: Wi_solv + gather_sol(1)
  s = { uS[1] + 544, KU, wib[1], KWI, biasWi[1], sS[1], HD, KWI, GB, 2,
        uS[0], sS[0], a2aP[0] };
  slot_kernel<0, 4><<<TOTAL, 512, 0, stream>>>(s);
  // S3..S8: WhC iterations, staggered (sides alternate gemm/gather)
  for (int it = 0; it < 3; ++it) {
    s = { uS[0], KU, whc[0], KU, bc[0], sS[0], HD, KU, GB, 2,
          uS[1], sS[1], a2aP[1] };
    slot_kernel<0, 4><<<TOTAL, 512, 0, stream>>>(s);
    if (it < 2) {
      s = { uS[1], KU, whc[1], KU, bc[1], sS[1], HD, KU, GB, 2,
            uS[0], sS[0], a2aP[0] };
      slot_kernel<0, 4><<<TOTAL, 512, 0, stream>>>(s);
    }
  }
  // S8: WhC3_solv + gather_sol(4)
  s = { uS[1], KU, whc[1], KU, bc[1], sS[1], HD, KU, GB, 2,
        uS[0], sS[0], a2aP[0] };
  slot_kernel<0, 4><<<TOTAL, 512, 0, stream>>>(s);
  // S9: Wo_sol + gather_solv(4)
  s = { uS[0], KU, wob[0], KU, biasWo[0], sS[0], HD, KU, GB, 2,
        uS[1], sS[1], a2aP[1] };
  slot_kernel<2, 4><<<TOTAL, 512, 0, stream>>>(s);
  // S10: Wo_solv (gemm only)
  s = { uS[1], KU, wob[1], KU, biasWo[1], sS[1], HD, KU, GB, 1,
        nullptr, nullptr, nullptr };
  slot_kernel<2, 4><<<GB, 512, 0, stream>>>(s);

  readout<<<2 * NMOL, 256, 0, stream>>>(wS, sX, wEnc, NMOL);

  const float* ffn1_w = (const float*)d_in[20];
  const float* ffn1_b = (const float*)d_in[21];
  const float* ffn2_w = (const float*)d_in[22];
  const float* ffn2_b = (const float*)d_in[23];

  convw<<<(NHID * 1024) / 256, 256, 0, stream>>>(wF1B, ffn1_w, nullptr, 1024, 1024, NHID, 0);
  s = { wEnc, 1024, wF1B, 1024, ffn1_b, wFF1, NHID, 1024, 16, 1,
        nullptr, nullptr, nullptr };
  slot_kernel<2, 2><<<16, 512, 0, stream>>>(s);
  ffn2_red<<<NMOL, 256, 0, stream>>>(wFF1, ffn2_w, ffn2_b, (float*)d_out);
}

// Round 15
// 978.036 us; speedup vs baseline: 1.0318x; 1.0318x over previous
//
#include <hip/hip_runtime.h>
#include <hip/hip_bf16.h>
#include <cstdint>
#include <cstddef>

#define A_REAL 50000
#define A_PAD  50176      // 196 * 256
#define MT256  196
#define PADROWS 176
#define NBOND  6
#define HD     512
#define FATOM  133
#define FBOND  14
#define KWI    160        // f_atoms block width (133 padded)
#define KU     704        // unified row: nei(512) | bond(32) | f_atoms(160)
#define NMOL   2000
#define MOLPAD 2048
#define APM    25
#define NHID   256

typedef __bf16 bf16x8 __attribute__((ext_vector_type(8)));
typedef float  f32x4  __attribute__((ext_vector_type(4)));
typedef short  short8 __attribute__((ext_vector_type(8)));
typedef short  short4v __attribute__((ext_vector_type(4)));

__device__ __forceinline__ float b2f(unsigned short u) {
  return __uint_as_float(((unsigned int)u) << 16);
}
__device__ __forceinline__ unsigned short f2b(float f) {
  unsigned int x = __float_as_uint(f);
  unsigned int r = (x + 0x7fffu + ((x >> 16) & 1u)) >> 16;
  return (unsigned short)r;
}
__device__ __forceinline__ unsigned short f2h(float f) {
  _Float16 h = (_Float16)f;                 // v_cvt_f16_f32, RNE
  return *(unsigned short*)&h;
}
__device__ __forceinline__ float h2f(unsigned short u) {
  _Float16 h = *(_Float16*)&u;
  return (float)h;
}

// ---------------- zero pad rows of wU (both sides) + wEnc pad ----------------
__global__ void zero_pads(unsigned short* __restrict__ wU, unsigned long long sU,
                          unsigned short* __restrict__ wEnc)
{
  const int t = blockIdx.x * 256 + threadIdx.x;
  if (t < PADROWS * KU) {
    wU[(size_t)A_REAL * KU + t] = 0;
    wU[sU + (size_t)A_REAL * KU + t] = 0;
  }
  if (t < 48 * 1024) wEnc[(size_t)NMOL * 1024 + t] = 0;
}

// ---------------- f32 weights -> padded bf16 ---------------------------------
// mode 0: plain pad. mode 1: Wo -> KU layout. mode 2: Wh+Wi combined -> KU.
__global__ void convw(unsigned short* __restrict__ dst, const float* __restrict__ src,
                      const float* __restrict__ srcB,
                      int Ksrc, int ldd, int rows, int mode)
{
  const int idx = blockIdx.x * 256 + threadIdx.x;
  if (idx >= rows * ldd) return;
  const int n = idx / ldd, k = idx % ldd;
  float v = 0.f;
  if (mode == 0) {
    if (k < Ksrc) v = src[(size_t)n * Ksrc + k];
  } else if (mode == 1) {
    if (k < 512)                  v = src[(size_t)n * 645 + 133 + k];
    else if (k >= 544 && k < 677) v = src[(size_t)n * 645 + (k - 544)];
  } else {
    if (k < 526)                  v = src[(size_t)n * 526 + k];
    else if (k >= 544 && k < 677) v = srcB[(size_t)n * 133 + (k - 544)];
  }
  dst[(size_t)n * ldd + k] = f2b(v);
}

// ---------------- combined bias bh + bi (f32) --------------------------------
__global__ void bias_comb(float* __restrict__ dst, const float* __restrict__ bh,
                          const float* __restrict__ bi)
{
  const int t = blockIdx.x * 256 + threadIdx.x;
  if (t < HD) dst[t] = bh[t] + bi[t];
}

// ---------------- f_atoms -> wU cols 544..703 (bf16, padded) -----------------
__global__ void atoms_prep(unsigned short* __restrict__ wU, const float* __restrict__ f_atoms)
{
  const int idx = blockIdx.x * 256 + threadIdx.x;
  if (idx >= A_PAD * KWI) return;
  const int r = idx / KWI, c = idx % KWI;
  float v = 0.f;
  if (r < A_REAL && c < FATOM) v = f_atoms[(size_t)r * FATOM + c];
  wU[(size_t)r * KU + 544 + c] = f2b(v);
}

// ---------------- bond gather-sum -> wU cols 512..543 (once per side) --------
__global__ void bond_gather(unsigned short* __restrict__ wU, const float* __restrict__ f_bonds,
                            const int* __restrict__ a2b)
{
  const int a = blockIdx.x * 256 + threadIdx.x;
  if (a >= A_REAL) return;
  float acc[FBOND];
  #pragma unroll
  for (int c = 0; c < FBOND; ++c) acc[c] = 0.f;
  #pragma unroll
  for (int j = 0; j < NBOND; ++j) {
    const int b = a2b[a * NBOND + j];
    const float* row = f_bonds + (size_t)b * FBOND;
    #pragma unroll
    for (int c = 0; c < FBOND; ++c) acc[c] += row[c];
  }
  unsigned short* d = wU + (size_t)a * KU + 512;
  #pragma unroll
  for (int c = 0; c < FBOND; ++c) d[c] = f2b(acc[c]);
  #pragma unroll
  for (int c = FBOND; c < 32; ++c) d[c] = 0;
}

// ============ SLOT KERNEL: intra-block role fusion ===========================
// r13 (1:8 block interleave, 927us) / r14 (1:1, 1009us) post-mortem: both
// roles share one 48KB-LDS kernel, so every gather BLOCK occupies a
// GEMM-sized residency slot -> GEMM density diluted (r14) or GEMM queued
// behind gathers (r13). Block-level interleave can't fix this.
// r15: BOTH ROLES IN EACH BLOCK -- 784 blocks/slot, each runs the r11 GEMM
// AND a 64-atom gather chunk (other side), order flipped by bid&1 (half
// gather-first, half gemm-first). Every CU holds ~3 mixed-phase blocks:
// gather (memory pipe) overlaps neighbors' MFMA (m114), no residency
// dilution, no single-role tail. Roles are data-independent within a slot
// and block-uniform (no divergent barriers). Numerics identical to r13.
// GEMM: C[M x N] = A[M x K] * W[N x K]^T, bf16 in, fp32 accum, fp16 out.
// MODE 0: out = fp16(acc + bias)   MODE 2: out = fp16(relu(acc + bias))
struct SlotP {
  // gemm role (single side, pre-resolved pointers)
  const unsigned short* A; int lda;
  const unsigned short* W; int ldb;
  const float* bias;
  unsigned short* out; int outLd;
  int K; int gB; int R;
  // gather role (other side), active when R > 1
  unsigned short* gDst;               // side's wU (nei cols 0..511)
  const unsigned short* gState;       // side's fp16 state
  const int* a2a;
};

__device__ __forceinline__ void gather_role(const SlotP& p, int bid, int tid)
{
  const int wv   = tid >> 6;
  const int lane = tid & 63;
  #pragma unroll
  for (int k = 0; k < 8; ++k) {
    const int a = bid * 64 + k * 8 + wv;
    if (a < A_REAL) {
      const int* idx = p.a2a + a * NBOND;
      float acc[8] = {0.f,0.f,0.f,0.f,0.f,0.f,0.f,0.f};
      #pragma unroll
      for (int j = 0; j < NBOND; ++j) {
        const int r0 = idx[j];
        short8 v = *reinterpret_cast<const short8*>(p.gState + (size_t)r0 * HD + lane * 8);
        #pragma unroll
        for (int e = 0; e < 8; ++e) acc[e] += fmaxf(h2f((unsigned short)v[e]), 0.f);
      }
      short8 o;
      #pragma unroll
      for (int e = 0; e < 8; ++e) o[e] = (short)f2b(acc[e]);
      *reinterpret_cast<short8*>(p.gDst + (size_t)a * KU + lane * 8) = o;
    }
  }
}

template<int MODE, int NTN>
__launch_bounds__(512, 4)
__global__ void slot_kernel(SlotP p)
{
  __shared__ alignas(16) unsigned short lA[2][256 * 32];
  __shared__ alignas(16) unsigned short lB[2][128 * 32];
  const int tid = threadIdx.x;
  const int bid = blockIdx.x;

  const bool hasG   = (p.R > 1);
  const bool gFirst = hasG && (bid & 1);

  if (gFirst) gather_role(p, bid, tid);

  // ---- gemm role: r11 body (ring-2, T2 swizzle, setprio) ----
  const int lane = tid & 63;
  const int wav  = tid >> 6;
  const int wm = wav >> 1, wn = wav & 1;

  // bijective chunked XCD swizzle over gemm sub-grid (gB % 8 == 0)
  const int nwg = p.gB;
  const int q2 = nwg >> 3, r2 = nwg & 7;
  const int xcd = bid & 7, jj = bid >> 3;
  const int gid = (xcd < r2 ? xcd * (q2 + 1) : r2 * (q2 + 1) + (xcd - r2) * q2) + jj;
  const int bxt = gid / NTN;
  const int byt = gid - bxt * NTN;
  const size_t tileM = (size_t)bxt * 256;
  const int n0 = byt * 128;

  const int srow = tid >> 2;
  const int sgcol = (((tid & 3) ^ ((tid >> 3) & 3)) * 8);  // T2 pre-swizzled chunk
  const int fr = lane & 15;
  const int xr = ((lane & 15) >> 1) & 3;
  const int fks = (((lane >> 4) ^ xr) * 8);

  f32x4 acc[4][4];
  #pragma unroll
  for (int m = 0; m < 4; ++m)
    #pragma unroll
    for (int n = 0; n < 4; ++n)
      acc[m][n] = (f32x4){0.f, 0.f, 0.f, 0.f};

  const unsigned short* Abase = p.A + tileM * (size_t)p.lda;
  const unsigned short* Wbase = p.W + (size_t)n0 * (size_t)p.ldb;
  const int lda = p.lda, ldb = p.ldb;
  const int nt = p.K >> 5;

  auto stage = [&](int t, int buf) {
    const int k0 = t * 32;
    #pragma unroll
    for (int i = 0; i < 2; ++i) {
      const int rr = i * 128 + srow;
      const unsigned short* ga = Abase + (size_t)rr * lda + (k0 + sgcol);
      __builtin_amdgcn_global_load_lds(
          (const __attribute__((address_space(1))) unsigned int*)ga,
          (__attribute__((address_space(3))) unsigned int*)&lA[buf][rr * 32 + (tid & 3) * 8], 16, 0, 0);
    }
    const unsigned short* gb = Wbase + (size_t)srow * ldb + (k0 + sgcol);
    __builtin_amdgcn_global_load_lds(
        (const __attribute__((address_space(1))) unsigned int*)gb,
        (__attribute__((address_space(3))) unsigned int*)&lB[buf][srow * 32 + (tid & 3) * 8], 16, 0, 0);
  };

  stage(0, 0);

  int buf = 0;
  for (int t = 0; t < nt; ++t) {
    asm volatile("s_waitcnt vmcnt(0)" ::: "memory");
    __builtin_amdgcn_s_barrier();
    asm volatile("" ::: "memory");

    bf16x8 af[4], bfm[4];
    #pragma unroll
    for (int m = 0; m < 4; ++m)
      af[m] = *reinterpret_cast<const bf16x8*>(&lA[buf][(wm * 64 + m * 16 + fr) * 32 + fks]);
    #pragma unroll
    for (int n = 0; n < 4; ++n)
      bfm[n] = *reinterpret_cast<const bf16x8*>(&lB[buf][(wn * 64 + n * 16 + fr) * 32 + fks]);

    if (t + 1 < nt) stage(t + 1, buf ^ 1);

    __builtin_amdgcn_s_setprio(1);
    // operand-swapped: lane = M-row, 4 acc regs = 4 consecutive N cols
    #pragma unroll
    for (int m = 0; m < 4; ++m)
      #pragma unroll
      for (int n = 0; n < 4; ++n)
        acc[m][n] = __builtin_amdgcn_mfma_f32_16x16x32_bf16(bfm[n], af[m], acc[m][n], 0, 0, 0);
    __builtin_amdgcn_s_setprio(0);

    buf ^= 1;
  }

  const int erow = lane & 15;
  const int ecol = (lane >> 4) * 4;
  #pragma unroll
  for (int m = 0; m < 4; ++m) {
    const size_t rowg = tileM + wm * 64 + m * 16 + erow;
    #pragma unroll
    for (int n = 0; n < 4; ++n) {
      const int colg = n0 + wn * 64 + n * 16 + ecol;
      const f32x4 bv = *reinterpret_cast<const f32x4*>(&p.bias[colg]);
      const size_t off = rowg * (size_t)p.outLd + colg;
      float v[4];
      #pragma unroll
      for (int e = 0; e < 4; ++e) v[e] = acc[m][n][e] + bv[e];
      short4v o;
      if (MODE == 0) {
        #pragma unroll
        for (int e = 0; e < 4; ++e) o[e] = (short)f2h(v[e]);
      } else {
        #pragma unroll
        for (int e = 0; e < 4; ++e) o[e] = (short)f2h(fmaxf(v[e], 0.f));
      }
      *reinterpret_cast<short4v*>(&p.out[off]) = o;
    }
  }

  if (hasG && !gFirst) gather_role(p, bid, tid);
}

// ---------------- per-molecule mean over 25 atoms -> enc (bf16), dual-side ---
__launch_bounds__(256)
__global__ void readout(const unsigned short* __restrict__ h, unsigned long long sH,
                        unsigned short* __restrict__ enc, int bps)
{
  const int blk = blockIdx.x;
  const int s   = blk / bps;
  const int mol = blk - s * bps;
  const int t = threadIdx.x;
  const unsigned short* base = h + s * sH + (size_t)mol * APM * HD + t * 2;
  float s0 = 0.f, s1 = 0.f;
  #pragma unroll
  for (int r = 0; r < APM; ++r) {
    unsigned int v = *reinterpret_cast<const unsigned int*>(base + (size_t)r * HD);
    s0 += h2f((unsigned short)(v & 0xffffu));
    s1 += h2f((unsigned short)(v >> 16));
  }
  s0 *= (1.f / 25.f);
  s1 *= (1.f / 25.f);
  unsigned int o = (unsigned int)f2b(s0) | ((unsigned int)f2b(s1) << 16);
  *reinterpret_cast<unsigned int*>(enc + (size_t)mol * 1024 + s * HD + t * 2) = o;
}

// ---------------- final dot with ffn2 (ff1 is fp16) --------------------------
__launch_bounds__(256)
__global__ void ffn2_red(const unsigned short* __restrict__ ff1, const float* __restrict__ w2,
                         const float* __restrict__ b2, float* __restrict__ out)
{
  __shared__ float red[256];
  const int mol = blockIdx.x, t = threadIdx.x;
  red[t] = h2f(ff1[(size_t)mol * NHID + t]) * w2[t];
  __syncthreads();
  #pragma unroll
  for (int s = 128; s > 0; s >>= 1) {
    if (t < s) red[t] += red[t + s];
    __syncthreads();
  }
  if (t == 0) out[mol] = red[0] + b2[0];
}

// -----------------------------------------------------------------------------
extern "C" void kernel_launch(void* const* d_in, const int* in_sizes, int n_in,
                              void* d_out, int out_size, void* d_ws, size_t ws_size,
                              hipStream_t stream)
{
  (void)in_sizes; (void)n_in; (void)out_size; (void)ws_size;

  unsigned char* p = (unsigned char*)d_ws;
  auto take = [&](size_t bytes) -> unsigned short* {
    unsigned short* r = (unsigned short*)p;
    p += (bytes + 1023) & ~(size_t)1023;
    return r;
  };
  const unsigned long long sX = (unsigned long long)A_PAD * HD;   // elems
  const unsigned long long sU = (unsigned long long)A_PAD * KU;
  unsigned short* wS   = take((size_t)2 * sX * 2);   // fp16 state s / h
  unsigned short* wU   = take((size_t)2 * sU * 2);   // bf16 [nei|bond|f_atoms]
  unsigned short* wEnc = take((size_t)MOLPAD * 1024 * 2);   // bf16
  unsigned short* wFF1 = take((size_t)MOLPAD * NHID * 2);   // fp16
  unsigned short* wWiB = take((size_t)2 * 512 * KWI * 2);
  unsigned short* wWhC = take((size_t)2 * 512 * KU * 2);    // [Wh|0|Wi]
  unsigned short* wWoB = take((size_t)2 * 512 * KU * 2);
  unsigned short* wF1B = take((size_t)NHID * 1024 * 2);
  float*          wBC  = (float*)take((size_t)2 * HD * 4);  // bh+bi

  unsigned short* wS0 = wS;            unsigned short* wS1 = wS + sX;
  unsigned short* wU0 = wU;            unsigned short* wU1 = wU + sU;

  const float* biasWi[2]; const float* biasWo[2];
  const int* a2aP[2];
  for (int s = 0; s < 2; ++s) {
    biasWi[s] = (const float*)d_in[s * 10 + 5];
    biasWo[s] = (const float*)d_in[s * 10 + 9];
    a2aP[s]   = (const int*)  d_in[s * 10 + 2];
  }

  zero_pads<<<484, 256, 0, stream>>>(wU, sU, wEnc);

  for (int side = 0; side < 2; ++side) {
    const float* f_atoms = (const float*)d_in[side * 10 + 0];
    const float* f_bonds = (const float*)d_in[side * 10 + 1];
    const int*   a2b     = (const int*)  d_in[side * 10 + 3];
    const float* Wi_w    = (const float*)d_in[side * 10 + 4];
    const float* Wi_b    = (const float*)d_in[side * 10 + 5];
    const float* Wh_w    = (const float*)d_in[side * 10 + 6];
    const float* Wh_b    = (const float*)d_in[side * 10 + 7];
    const float* Wo_w    = (const float*)d_in[side * 10 + 8];
    convw<<<(512 * KWI) / 256, 256, 0, stream>>>(wWiB + side * 512 * KWI, Wi_w, nullptr,
                                                 FATOM, KWI, 512, 0);
    convw<<<(512 * KU) / 256, 256, 0, stream>>>(wWhC + side * 512 * KU, Wh_w, Wi_w,
                                                526, KU, 512, 2);
    convw<<<(512 * KU) / 256, 256, 0, stream>>>(wWoB + side * 512 * KU, Wo_w, nullptr,
                                                645, KU, 512, 1);
    bias_comb<<<2, 256, 0, stream>>>(wBC + side * HD, Wh_b, Wi_b);
    atoms_prep<<<(A_PAD * KWI) / 256, 256, 0, stream>>>(wU + side * sU, f_atoms);
    bond_gather<<<(A_REAL + 255) / 256, 256, 0, stream>>>(wU + side * sU, f_bonds, a2b);
  }

  const int GB = MT256 * 4;        // 784 blocks/slot (each: gemm + gather)

  unsigned short* uS[2] = { wU0, wU1 };
  unsigned short* sS[2] = { wS0, wS1 };
  const unsigned short* whc[2] = { wWhC, wWhC + 512 * KU };
  const unsigned short* wob[2] = { wWoB, wWoB + 512 * KU };
  const unsigned short* wib[2] = { wWiB, wWiB + 512 * KWI };
  const float* bc[2] = { wBC, wBC + HD };

  SlotP s;
  // S1: Wi_sol (gemm only)
  s = { uS[0] + 544, KU, wib[0], KWI, biasWi[0], sS[0], HD, KWI, GB, 1,
        nullptr, nullptr, nullptr };
  slot_kernel<0, 4><<<GB, 512, 0, stream>>>(s);
  // S2: Wi_solv + gather_sol(1)
  s = { uS[1] + 544, KU, wib[1], KWI, biasWi[1], sS[1], HD, KWI, GB, 2,
        uS[0], sS[0], a2aP[0] };
  slot_kernel<0, 4><<<GB, 512, 0, stream>>>(s);
  // S3..S8: WhC iterations, staggered (sides alternate gemm/gather)
  for (int it = 0; it < 3; ++it) {
    s = { uS[0], KU, whc[0], KU, bc[0], sS[0], HD, KU, GB, 2,
          uS[1], sS[1], a2aP[1] };
    slot_kernel<0, 4><<<GB, 512, 0, stream>>>(s);
    if (it < 2) {
      s = { uS[1], KU, whc[1], KU, bc[1], sS[1], HD, KU, GB, 2,
            uS[0], sS[0], a2aP[0] };
      slot_kernel<0, 4><<<GB, 512, 0, stream>>>(s);
    }
  }
  // S8: WhC3_solv + gather_sol(4)
  s = { uS[1], KU, whc[1], KU, bc[1], sS[1], HD, KU, GB, 2,
        uS[0], sS[0], a2aP[0] };
  slot_kernel<0, 4><<<GB, 512, 0, stream>>>(s);
  // S9: Wo_sol + gather_solv(4)
  s = { uS[0], KU, wob[0], KU, biasWo[0], sS[0], HD, KU, GB, 2,
        uS[1], sS[1], a2aP[1] };
  slot_kernel<2, 4><<<GB, 512, 0, stream>>>(s);
  // S10: Wo_solv (gemm only)
  s = { uS[1], KU, wob[1], KU, biasWo[1], sS[1], HD, KU, GB, 1,
        nullptr, nullptr, nullptr };
  slot_kernel<2, 4><<<GB, 512, 0, stream>>>(s);

  readout<<<2 * NMOL, 256, 0, stream>>>(wS, sX, wEnc, NMOL);

  const float* ffn1_w = (const float*)d_in[20];
  const float* ffn1_b = (const float*)d_in[21];
  const float* ffn2_w = (const float*)d_in[22];
  const float* ffn2_b = (const float*)d_in[23];

  convw<<<(NHID * 1024) / 256, 256, 0, stream>>>(wF1B, ffn1_w, nullptr, 1024, 1024, NHID, 0);
  s = { wEnc, 1024, wF1B, 1024, ffn1_b, wFF1, NHID, 1024, 16, 1,
        nullptr, nullptr, nullptr };
  slot_kernel<2, 2><<<16, 512, 0, stream>>>(s);
  ffn2_red<<<NMOL, 256, 0, stream>>>(wFF1, ffn2_w, ffn2_b, (float*)d_out);
}

// Round 16
// 929.709 us; speedup vs baseline: 1.0854x; 1.0520x over previous
//
#include <hip/hip_runtime.h>
#include <hip/hip_bf16.h>
#include <cstdint>
#include <cstddef>

#define A_REAL 50000
#define A_PAD  50176      // 196 * 256
#define MT256  196
#define PADROWS 176
#define NBOND  6
#define HD     512
#define FATOM  133
#define FBOND  14
#define KWI    160        // f_atoms block width (133 padded)
#define KU     704        // unified row: nei(512) | bond(32) | f_atoms(160)
#define NMOL   2000
#define MOLPAD 2048
#define APM    25
#define NHID   256

typedef __bf16 bf16x8 __attribute__((ext_vector_type(8)));
typedef float  f32x4  __attribute__((ext_vector_type(4)));
typedef short  short8 __attribute__((ext_vector_type(8)));
typedef short  short4v __attribute__((ext_vector_type(4)));

__device__ __forceinline__ float b2f(unsigned short u) {
  return __uint_as_float(((unsigned int)u) << 16);
}
__device__ __forceinline__ unsigned short f2b(float f) {
  unsigned int x = __float_as_uint(f);
  unsigned int r = (x + 0x7fffu + ((x >> 16) & 1u)) >> 16;
  return (unsigned short)r;
}
__device__ __forceinline__ unsigned short f2h(float f) {
  _Float16 h = (_Float16)f;                 // v_cvt_f16_f32, RNE
  return *(unsigned short*)&h;
}
__device__ __forceinline__ float h2f(unsigned short u) {
  _Float16 h = *(_Float16*)&u;
  return (float)h;
}

// ---------------- zero pad rows of wU (both sides) + wEnc pad ----------------
__global__ void zero_pads(unsigned short* __restrict__ wU, unsigned long long sU,
                          unsigned short* __restrict__ wEnc)
{
  const int t = blockIdx.x * 256 + threadIdx.x;
  if (t < PADROWS * KU) {
    wU[(size_t)A_REAL * KU + t] = 0;
    wU[sU + (size_t)A_REAL * KU + t] = 0;
  }
  if (t < 48 * 1024) wEnc[(size_t)NMOL * 1024 + t] = 0;
}

// ---------------- f32 weights -> padded bf16 ---------------------------------
// mode 0: plain pad. mode 1: Wo -> KU layout. mode 2: Wh+Wi combined -> KU.
__global__ void convw(unsigned short* __restrict__ dst, const float* __restrict__ src,
                      const float* __restrict__ srcB,
                      int Ksrc, int ldd, int rows, int mode)
{
  const int idx = blockIdx.x * 256 + threadIdx.x;
  if (idx >= rows * ldd) return;
  const int n = idx / ldd, k = idx % ldd;
  float v = 0.f;
  if (mode == 0) {
    if (k < Ksrc) v = src[(size_t)n * Ksrc + k];
  } else if (mode == 1) {
    if (k < 512)                  v = src[(size_t)n * 645 + 133 + k];
    else if (k >= 544 && k < 677) v = src[(size_t)n * 645 + (k - 544)];
  } else {
    if (k < 526)                  v = src[(size_t)n * 526 + k];
    else if (k >= 544 && k < 677) v = srcB[(size_t)n * 133 + (k - 544)];
  }
  dst[(size_t)n * ldd + k] = f2b(v);
}

// ---------------- combined bias bh + bi (f32) --------------------------------
__global__ void bias_comb(float* __restrict__ dst, const float* __restrict__ bh,
                          const float* __restrict__ bi)
{
  const int t = blockIdx.x * 256 + threadIdx.x;
  if (t < HD) dst[t] = bh[t] + bi[t];
}

// ---------------- f_atoms -> wU cols 544..703 (bf16, padded) -----------------
__global__ void atoms_prep(unsigned short* __restrict__ wU, const float* __restrict__ f_atoms)
{
  const int idx = blockIdx.x * 256 + threadIdx.x;
  if (idx >= A_PAD * KWI) return;
  const int r = idx / KWI, c = idx % KWI;
  float v = 0.f;
  if (r < A_REAL && c < FATOM) v = f_atoms[(size_t)r * FATOM + c];
  wU[(size_t)r * KU + 544 + c] = f2b(v);
}

// ---------------- bond gather-sum -> wU cols 512..543 (once per side) --------
__global__ void bond_gather(unsigned short* __restrict__ wU, const float* __restrict__ f_bonds,
                            const int* __restrict__ a2b)
{
  const int a = blockIdx.x * 256 + threadIdx.x;
  if (a >= A_REAL) return;
  float acc[FBOND];
  #pragma unroll
  for (int c = 0; c < FBOND; ++c) acc[c] = 0.f;
  #pragma unroll
  for (int j = 0; j < NBOND; ++j) {
    const int b = a2b[a * NBOND + j];
    const float* row = f_bonds + (size_t)b * FBOND;
    #pragma unroll
    for (int c = 0; c < FBOND; ++c) acc[c] += row[c];
  }
  unsigned short* d = wU + (size_t)a * KU + 512;
  #pragma unroll
  for (int c = 0; c < FBOND; ++c) d[c] = f2b(acc[c]);
  #pragma unroll
  for (int c = FBOND; c < 32; ++c) d[c] = 0;
}

// ============ SLOT KERNEL: role-split co-dispatch (r13 champion) =============
// Every R-th block (bid%R==0, R=9 -> gemm blocks cycle XCDs) runs the r11
// single-side GEMM (256x128 tile, ring-2, T2 swizzle); all other blocks run
// the gather (8 atoms/block, wave-per-atom, coalesced 1KB-row reads).
// r13=927 / r14(1:1)=1009 / r15(intra-block)=978: mixed slots are ~additive
// (GEMM 58 + gather 50 ~= 100us) in every arrangement -- shared constraint
// is the gather's random-1KB-row DRAM efficiency (~3 TB/s), not scheduling.
// This is the measured-best arrangement; re-anchoring per rigor discipline.
// GEMM: C[M x N] = A[M x K] * W[N x K]^T, bf16 in, fp32 accum, fp16 out.
// MODE 0: out = fp16(acc + bias)   MODE 2: out = fp16(relu(acc + bias))
struct SlotP {
  // gemm role (single side, pre-resolved pointers)
  const unsigned short* A; int lda;
  const unsigned short* W; int ldb;
  const float* bias;
  unsigned short* out; int outLd;
  int K; int gB; int R;
  // gather role (other side), active when R > 1
  unsigned short* gDst;               // side's wU (nei cols 0..511)
  const unsigned short* gState;       // side's fp16 state
  const int* a2a;
};

template<int MODE, int NTN>
__launch_bounds__(512, 4)
__global__ void slot_kernel(SlotP p)
{
  __shared__ alignas(16) unsigned short lA[2][256 * 32];
  __shared__ alignas(16) unsigned short lB[2][128 * 32];
  const int tid = threadIdx.x;
  const int bid = blockIdx.x;

  int gi = bid;
  bool isg = true;
  int hi = 0;
  if (p.R > 1) {
    const int qq = bid / p.R, rr = bid - qq * p.R;
    if (rr == 0 && qq < p.gB) {
      gi = qq;
    } else {
      isg = false;
      hi = (qq < p.gB) ? (bid - qq - 1) : (bid - p.gB);
    }
  }

  if (!isg) {
    // ---- gather role: 8 atoms/block, wave-per-atom ----
    const int wv   = tid >> 6;
    const int lane = tid & 63;
    const int a = hi * 8 + wv;
    if (a < A_REAL) {
      const int* idx = p.a2a + a * NBOND;
      float acc[8] = {0.f,0.f,0.f,0.f,0.f,0.f,0.f,0.f};
      #pragma unroll
      for (int j = 0; j < NBOND; ++j) {
        const int r0 = idx[j];
        short8 v = *reinterpret_cast<const short8*>(p.gState + (size_t)r0 * HD + lane * 8);
        #pragma unroll
        for (int e = 0; e < 8; ++e) acc[e] += fmaxf(h2f((unsigned short)v[e]), 0.f);
      }
      short8 o;
      #pragma unroll
      for (int e = 0; e < 8; ++e) o[e] = (short)f2b(acc[e]);
      *reinterpret_cast<short8*>(p.gDst + (size_t)a * KU + lane * 8) = o;
    }
    return;
  }

  // ---- gemm role: r11 body (ring-2, T2 swizzle, setprio) ----
  const int lane = tid & 63;
  const int wav  = tid >> 6;
  const int wm = wav >> 1, wn = wav & 1;

  // bijective chunked XCD swizzle over gemm sub-grid (gB % 8 == 0)
  const int nwg = p.gB;
  const int q2 = nwg >> 3, r2 = nwg & 7;
  const int xcd = gi & 7, jj = gi >> 3;
  const int gid = (xcd < r2 ? xcd * (q2 + 1) : r2 * (q2 + 1) + (xcd - r2) * q2) + jj;
  const int bxt = gid / NTN;
  const int byt = gid - bxt * NTN;
  const size_t tileM = (size_t)bxt * 256;
  const int n0 = byt * 128;

  const int srow = tid >> 2;
  const int sgcol = (((tid & 3) ^ ((tid >> 3) & 3)) * 8);  // T2 pre-swizzled chunk
  const int fr = lane & 15;
  const int xr = ((lane & 15) >> 1) & 3;
  const int fks = (((lane >> 4) ^ xr) * 8);

  f32x4 acc[4][4];
  #pragma unroll
  for (int m = 0; m < 4; ++m)
    #pragma unroll
    for (int n = 0; n < 4; ++n)
      acc[m][n] = (f32x4){0.f, 0.f, 0.f, 0.f};

  const unsigned short* Abase = p.A + tileM * (size_t)p.lda;
  const unsigned short* Wbase = p.W + (size_t)n0 * (size_t)p.ldb;
  const int lda = p.lda, ldb = p.ldb;
  const int nt = p.K >> 5;

  auto stage = [&](int t, int buf) {
    const int k0 = t * 32;
    #pragma unroll
    for (int i = 0; i < 2; ++i) {
      const int rr = i * 128 + srow;
      const unsigned short* ga = Abase + (size_t)rr * lda + (k0 + sgcol);
      __builtin_amdgcn_global_load_lds(
          (const __attribute__((address_space(1))) unsigned int*)ga,
          (__attribute__((address_space(3))) unsigned int*)&lA[buf][rr * 32 + (tid & 3) * 8], 16, 0, 0);
    }
    const unsigned short* gb = Wbase + (size_t)srow * ldb + (k0 + sgcol);
    __builtin_amdgcn_global_load_lds(
        (const __attribute__((address_space(1))) unsigned int*)gb,
        (__attribute__((address_space(3))) unsigned int*)&lB[buf][srow * 32 + (tid & 3) * 8], 16, 0, 0);
  };

  stage(0, 0);

  int buf = 0;
  for (int t = 0; t < nt; ++t) {
    asm volatile("s_waitcnt vmcnt(0)" ::: "memory");
    __builtin_amdgcn_s_barrier();
    asm volatile("" ::: "memory");

    bf16x8 af[4], bfm[4];
    #pragma unroll
    for (int m = 0; m < 4; ++m)
      af[m] = *reinterpret_cast<const bf16x8*>(&lA[buf][(wm * 64 + m * 16 + fr) * 32 + fks]);
    #pragma unroll
    for (int n = 0; n < 4; ++n)
      bfm[n] = *reinterpret_cast<const bf16x8*>(&lB[buf][(wn * 64 + n * 16 + fr) * 32 + fks]);

    if (t + 1 < nt) stage(t + 1, buf ^ 1);

    __builtin_amdgcn_s_setprio(1);
    // operand-swapped: lane = M-row, 4 acc regs = 4 consecutive N cols
    #pragma unroll
    for (int m = 0; m < 4; ++m)
      #pragma unroll
      for (int n = 0; n < 4; ++n)
        acc[m][n] = __builtin_amdgcn_mfma_f32_16x16x32_bf16(bfm[n], af[m], acc[m][n], 0, 0, 0);
    __builtin_amdgcn_s_setprio(0);

    buf ^= 1;
  }

  const int erow = lane & 15;
  const int ecol = (lane >> 4) * 4;
  #pragma unroll
  for (int m = 0; m < 4; ++m) {
    const size_t rowg = tileM + wm * 64 + m * 16 + erow;
    #pragma unroll
    for (int n = 0; n < 4; ++n) {
      const int colg = n0 + wn * 64 + n * 16 + ecol;
      const f32x4 bv = *reinterpret_cast<const f32x4*>(&p.bias[colg]);
      const size_t off = rowg * (size_t)p.outLd + colg;
      float v[4];
      #pragma unroll
      for (int e = 0; e < 4; ++e) v[e] = acc[m][n][e] + bv[e];
      short4v o;
      if (MODE == 0) {
        #pragma unroll
        for (int e = 0; e < 4; ++e) o[e] = (short)f2h(v[e]);
      } else {
        #pragma unroll
        for (int e = 0; e < 4; ++e) o[e] = (short)f2h(fmaxf(v[e], 0.f));
      }
      *reinterpret_cast<short4v*>(&p.out[off]) = o;
    }
  }
}

// ---------------- per-molecule mean over 25 atoms -> enc (bf16), dual-side ---
__launch_bounds__(256)
__global__ void readout(const unsigned short* __restrict__ h, unsigned long long sH,
                        unsigned short* __restrict__ enc, int bps)
{
  const int blk = blockIdx.x;
  const int s   = blk / bps;
  const int mol = blk - s * bps;
  const int t = threadIdx.x;
  const unsigned short* base = h + s * sH + (size_t)mol * APM * HD + t * 2;
  float s0 = 0.f, s1 = 0.f;
  #pragma unroll
  for (int r = 0; r < APM; ++r) {
    unsigned int v = *reinterpret_cast<const unsigned int*>(base + (size_t)r * HD);
    s0 += h2f((unsigned short)(v & 0xffffu));
    s1 += h2f((unsigned short)(v >> 16));
  }
  s0 *= (1.f / 25.f);
  s1 *= (1.f / 25.f);
  unsigned int o = (unsigned int)f2b(s0) | ((unsigned int)f2b(s1) << 16);
  *reinterpret_cast<unsigned int*>(enc + (size_t)mol * 1024 + s * HD + t * 2) = o;
}

// ---------------- final dot with ffn2 (ff1 is fp16) --------------------------
__launch_bounds__(256)
__global__ void ffn2_red(const unsigned short* __restrict__ ff1, const float* __restrict__ w2,
                         const float* __restrict__ b2, float* __restrict__ out)
{
  __shared__ float red[256];
  const int mol = blockIdx.x, t = threadIdx.x;
  red[t] = h2f(ff1[(size_t)mol * NHID + t]) * w2[t];
  __syncthreads();
  #pragma unroll
  for (int s = 128; s > 0; s >>= 1) {
    if (t < s) red[t] += red[t + s];
    __syncthreads();
  }
  if (t == 0) out[mol] = red[0] + b2[0];
}

// -----------------------------------------------------------------------------
extern "C" void kernel_launch(void* const* d_in, const int* in_sizes, int n_in,
                              void* d_out, int out_size, void* d_ws, size_t ws_size,
                              hipStream_t stream)
{
  (void)in_sizes; (void)n_in; (void)out_size; (void)ws_size;

  unsigned char* p = (unsigned char*)d_ws;
  auto take = [&](size_t bytes) -> unsigned short* {
    unsigned short* r = (unsigned short*)p;
    p += (bytes + 1023) & ~(size_t)1023;
    return r;
  };
  const unsigned long long sX = (unsigned long long)A_PAD * HD;   // elems
  const unsigned long long sU = (unsigned long long)A_PAD * KU;
  unsigned short* wS   = take((size_t)2 * sX * 2);   // fp16 state s / h
  unsigned short* wU   = take((size_t)2 * sU * 2);   // bf16 [nei|bond|f_atoms]
  unsigned short* wEnc = take((size_t)MOLPAD * 1024 * 2);   // bf16
  unsigned short* wFF1 = take((size_t)MOLPAD * NHID * 2);   // fp16
  unsigned short* wWiB = take((size_t)2 * 512 * KWI * 2);
  unsigned short* wWhC = take((size_t)2 * 512 * KU * 2);    // [Wh|0|Wi]
  unsigned short* wWoB = take((size_t)2 * 512 * KU * 2);
  unsigned short* wF1B = take((size_t)NHID * 1024 * 2);
  float*          wBC  = (float*)take((size_t)2 * HD * 4);  // bh+bi

  unsigned short* wS0 = wS;            unsigned short* wS1 = wS + sX;
  unsigned short* wU0 = wU;            unsigned short* wU1 = wU + sU;

  const float* biasWi[2]; const float* biasWo[2];
  const int* a2aP[2];
  for (int s = 0; s < 2; ++s) {
    biasWi[s] = (const float*)d_in[s * 10 + 5];
    biasWo[s] = (const float*)d_in[s * 10 + 9];
    a2aP[s]   = (const int*)  d_in[s * 10 + 2];
  }

  zero_pads<<<484, 256, 0, stream>>>(wU, sU, wEnc);

  for (int side = 0; side < 2; ++side) {
    const float* f_atoms = (const float*)d_in[side * 10 + 0];
    const float* f_bonds = (const float*)d_in[side * 10 + 1];
    const int*   a2b     = (const int*)  d_in[side * 10 + 3];
    const float* Wi_w    = (const float*)d_in[side * 10 + 4];
    const float* Wi_b    = (const float*)d_in[side * 10 + 5];
    const float* Wh_w    = (const float*)d_in[side * 10 + 6];
    const float* Wh_b    = (const float*)d_in[side * 10 + 7];
    const float* Wo_w    = (const float*)d_in[side * 10 + 8];
    convw<<<(512 * KWI) / 256, 256, 0, stream>>>(wWiB + side * 512 * KWI, Wi_w, nullptr,
                                                 FATOM, KWI, 512, 0);
    convw<<<(512 * KU) / 256, 256, 0, stream>>>(wWhC + side * 512 * KU, Wh_w, Wi_w,
                                                526, KU, 512, 2);
    convw<<<(512 * KU) / 256, 256, 0, stream>>>(wWoB + side * 512 * KU, Wo_w, nullptr,
                                                645, KU, 512, 1);
    bias_comb<<<2, 256, 0, stream>>>(wBC + side * HD, Wh_b, Wi_b);
    atoms_prep<<<(A_PAD * KWI) / 256, 256, 0, stream>>>(wU + side * sU, f_atoms);
    bond_gather<<<(A_REAL + 255) / 256, 256, 0, stream>>>(wU + side * sU, f_bonds, a2b);
  }

  const int GB = MT256 * 4;        // 784 gemm blocks (per side)
  const int RR = 9;                // gemm every 9th block -> XCD-cycling
  const int TOTAL = GB * RR;       // 7056: 784 gemm + 6272 gather (6250 used)

  unsigned short* uS[2] = { wU0, wU1 };
  unsigned short* sS[2] = { wS0, wS1 };
  const unsigned short* whc[2] = { wWhC, wWhC + 512 * KU };
  const unsigned short* wob[2] = { wWoB, wWoB + 512 * KU };
  const unsigned short* wib[2] = { wWiB, wWiB + 512 * KWI };
  const float* bc[2] = { wBC, wBC + HD };

  SlotP s;
  // S1: Wi_sol (gemm only)
  s = { uS[0] + 544, KU, wib[0], KWI, biasWi[0], sS[0], HD, KWI, GB, 1,
        nullptr, nullptr, nullptr };
  slot_kernel<0, 4><<<GB, 512, 0, stream>>>(s);
  // S2: Wi_solv + gather_sol(1)
  s = { uS[1] + 544, KU, wib[1], KWI, biasWi[1], sS[1], HD, KWI, GB, RR,
        uS[0], sS[0], a2aP[0] };
  slot_kernel<0, 4><<<TOTAL, 512, 0, stream>>>(s);
  // S3..S8: WhC iterations, staggered
  for (int it = 0; it < 3; ++it) {
    // gemm WhC_sol(it) + gather_solv(it+1 input)
    s = { uS[0], KU, whc[0], KU, bc[0], sS[0], HD, KU, GB, RR,
          uS[1], sS[1], a2aP[1] };
    slot_kernel<0, 4><<<TOTAL, 512, 0, stream>>>(s);
    if (it < 2) {
      s = { uS[1], KU, whc[1], KU, bc[1], sS[1], HD, KU, GB, RR,
            uS[0], sS[0], a2aP[0] };
      slot_kernel<0, 4><<<TOTAL, 512, 0, stream>>>(s);
    }
  }
  // S8: WhC3_solv + gather_sol(4)
  s = { uS[1], KU, whc[1], KU, bc[1], sS[1], HD, KU, GB, RR,
        uS[0], sS[0], a2aP[0] };
  slot_kernel<0, 4><<<TOTAL, 512, 0, stream>>>(s);
  // S9: Wo_sol + gather_solv(4)
  s = { uS[0], KU, wob[0], KU, biasWo[0], sS[0], HD, KU, GB, RR,
        uS[1], sS[1], a2aP[1] };
  slot_kernel<2, 4><<<TOTAL, 512, 0, stream>>>(s);
  // S10: Wo_solv (gemm only)
  s = { uS[1], KU, wob[1], KU, biasWo[1], sS[1], HD, KU, GB, 1,
        nullptr, nullptr, nullptr };
  slot_kernel<2, 4><<<GB, 512, 0, stream>>>(s);

  readout<<<2 * NMOL, 256, 0, stream>>>(wS, sX, wEnc, NMOL);

  const float* ffn1_w = (const float*)d_in[20];
  const float* ffn1_b = (const float*)d_in[21];
  const float* ffn2_w = (const float*)d_in[22];
  const float* ffn2_b = (const float*)d_in[23];

  convw<<<(NHID * 1024) / 256, 256, 0, stream>>>(wF1B, ffn1_w, nullptr, 1024, 1024, NHID, 0);
  s = { wEnc, 1024, wF1B, 1024, ffn1_b, wFF1, NHID, 1024, 16, 1,
        nullptr, nullptr, nullptr };
  slot_kernel<2, 2><<<16, 512, 0, stream>>>(s);
  ffn2_red<<<NMOL, 256, 0, stream>>>(wFF1, ffn2_w, ffn2_b, (float*)d_out);
}